// Round 3
// baseline (2974.139 us; speedup 1.0000x reference)
//
#include <hip/hip_runtime.h>

#define B_   1024
#define T_   512
#define I_   16
#define H_   50
#define FC_  64
#define HP   64     // padded H: 4 quarters x 16
#define HQ   16     // quarter size

__device__ __forceinline__ float sigm(float x)   { return 1.0f / (1.0f + __expf(-x)); }
__device__ __forceinline__ float tanh_f(float x) { return 1.0f - 2.0f / (1.0f + __expf(2.0f * x)); }

// One batch row per block. Lane layout (tid < 800): tid = 16*u + 4*q + s
//   u = LSTM unit (0..49), q = gate (i,f,g,o), s = dot-product quarter (0..3).
// 52 persistent weight floats/thread (spill-proof), c replicated in registers,
// h ping-pong in LDS (broadcast reads), 2 barriers/step.
// amdgpu_waves_per_eu(3,4): stop the allocator from spilling to chase 8 waves/EU.
__global__ __launch_bounds__(832) __attribute__((amdgpu_waves_per_eu(3, 4)))
void lstm_fused3(
    const float* __restrict__ x,
    const float* __restrict__ w_ih0, const float* __restrict__ w_hh0,
    const float* __restrict__ b_ih0, const float* __restrict__ b_hh0,
    const float* __restrict__ w_ih1, const float* __restrict__ w_hh1,
    const float* __restrict__ b_ih1, const float* __restrict__ b_hh1,
    const float* __restrict__ fc1_w, const float* __restrict__ fc1_b,
    const float* __restrict__ fc2_w, const float* __restrict__ fc2_b,
    float* __restrict__ out)
{
    __shared__ float h0s[2][HP], h1s[2][HP];
    __shared__ float xs[4][I_];              // x prefetch ring, distance 2

    const int tid  = threadIdx.x;
    const int row  = blockIdx.x;
    const int u    = tid >> 4;
    const int q    = (tid >> 2) & 3;
    const int s    = tid & 3;
    const bool gl  = tid < 800;
    const int g    = q * H_ + u;
    const int lb   = tid & ~12;              // lane of gate 0 in this (u,s) group
    const int l0 = lb, l1 = lb | 4, l2 = lb | 8, l3 = lb | 12;

    // ---- persistent per-thread weights: 4 + 3*16 = 52 floats ----
    float w0x[4], w0h[HQ], w1x[HQ], w1h[HQ];
    float bias0 = 0.f, bias1 = 0.f;
    if (gl) {
        #pragma unroll
        for (int i = 0; i < 4; ++i) w0x[i] = w_ih0[g * I_ + s * 4 + i];
        #pragma unroll
        for (int j = 0; j < HQ; ++j) {
            const int jj = s * HQ + j;
            const bool v = jj < H_;
            w0h[j] = v ? w_hh0[g * H_ + jj] : 0.f;
            w1x[j] = v ? w_ih1[g * H_ + jj] : 0.f;
            w1h[j] = v ? w_hh1[g * H_ + jj] : 0.f;
        }
        if (s == 0) {                        // bias counted once per gate
            bias0 = b_ih0[g] + b_hh0[g];
            bias1 = b_ih1[g] + b_hh1[g];
        }
    }

    if (tid < HP) {                          // zero h incl. padding
        h0s[0][tid] = 0.f; h0s[1][tid] = 0.f;
        h1s[0][tid] = 0.f; h1s[1][tid] = 0.f;
    }
    if (tid < 8) {                           // stage x(0), x(1)
        const int tt = tid >> 2, i4 = (tid & 3) * 4;
        *(float4*)&xs[tt][i4] = *(const float4*)(x + ((size_t)row * T_ + tt) * I_ + i4);
    }
    float c0 = 0.f, c1 = 0.f;
    __syncthreads();

    for (int t = 0; t < T_; ++t) {
        const int p = t & 1;                 // read h*[p], write h*[1-p]

        // ---- P0: layer-0 gates + cell update (x prefetch on idle lanes) ----
        if (gl) {
            float a = bias0, b2 = 0.f;
            const float4 xv = *((const float4*)xs[t & 3] + s);
            a += w0x[0]*xv.x + w0x[1]*xv.y + w0x[2]*xv.z + w0x[3]*xv.w;
            const float4* hp = (const float4*)h0s[p] + s * 4;
            #pragma unroll
            for (int k = 0; k < 4; ++k) {
                float4 hv = hp[k];
                if (k & 1) b2 += w0h[4*k]*hv.x + w0h[4*k+1]*hv.y + w0h[4*k+2]*hv.z + w0h[4*k+3]*hv.w;
                else       a  += w0h[4*k]*hv.x + w0h[4*k+1]*hv.y + w0h[4*k+2]*hv.z + w0h[4*k+3]*hv.w;
            }
            float pre = a + b2;
            pre += __shfl_xor(pre, 1);
            pre += __shfl_xor(pre, 2);       // full dot across 4 quarters
            const float act = (q == 2) ? tanh_f(pre) : sigm(pre);
            const float gi = __shfl(act, l0);
            const float gf = __shfl(act, l1);
            const float gg = __shfl(act, l2);
            const float go = __shfl(act, l3);
            c0 = gf * c0 + gi * gg;
            if ((tid & 15) == 0) h0s[1 - p][u] = go * tanh_f(c0);
        } else if (tid >= 800 && tid < 804) {
            if (t + 2 < T_) {
                const int i4 = (tid - 800) * 4;
                *(float4*)&xs[(t + 2) & 3][i4] =
                    *(const float4*)(x + ((size_t)row * T_ + t + 2) * I_ + i4);
            }
        }
        __syncthreads();

        // ---- P1: layer-1 gates + cell update ----
        if (gl) {
            float a = bias1, b2 = 0.f;
            const float4* h0p = (const float4*)h0s[1 - p] + s * 4;
            const float4* h1p = (const float4*)h1s[p]     + s * 4;
            #pragma unroll
            for (int k = 0; k < 4; ++k) {
                float4 hv = h0p[k];
                if (k & 1) b2 += w1x[4*k]*hv.x + w1x[4*k+1]*hv.y + w1x[4*k+2]*hv.z + w1x[4*k+3]*hv.w;
                else       a  += w1x[4*k]*hv.x + w1x[4*k+1]*hv.y + w1x[4*k+2]*hv.z + w1x[4*k+3]*hv.w;
            }
            #pragma unroll
            for (int k = 0; k < 4; ++k) {
                float4 hv = h1p[k];
                if (k & 1) b2 += w1h[4*k]*hv.x + w1h[4*k+1]*hv.y + w1h[4*k+2]*hv.z + w1h[4*k+3]*hv.w;
                else       a  += w1h[4*k]*hv.x + w1h[4*k+1]*hv.y + w1h[4*k+2]*hv.z + w1h[4*k+3]*hv.w;
            }
            float pre = a + b2;
            pre += __shfl_xor(pre, 1);
            pre += __shfl_xor(pre, 2);
            const float act = (q == 2) ? tanh_f(pre) : sigm(pre);
            const float gi = __shfl(act, l0);
            const float gf = __shfl(act, l1);
            const float gg = __shfl(act, l2);
            const float go = __shfl(act, l3);
            c1 = gf * c1 + gi * gg;
            if ((tid & 15) == 0) h1s[1 - p][u] = go * tanh_f(c1);
        }
        __syncthreads();
    }

    // ---- FC epilogue: final h1 in h1s[0] (T even) ----
    if (tid < FC_) {
        const float* hf = h1s[0];
        float a = fc1_b[tid];
        #pragma unroll
        for (int j = 0; j < H_; ++j) a += fc1_w[tid * H_ + j] * hf[j];
        float r = fmaxf(a, 0.f) * fc2_w[tid];
        #pragma unroll
        for (int off = 1; off < FC_; off <<= 1) r += __shfl_xor(r, off);
        if (tid == 0) out[row] = r + fc2_b[0];
    }
}

extern "C" void kernel_launch(void* const* d_in, const int* in_sizes, int n_in,
                              void* d_out, int out_size, void* d_ws, size_t ws_size,
                              hipStream_t stream) {
    const float* x     = (const float*)d_in[0];
    const float* w_ih0 = (const float*)d_in[1];
    const float* w_hh0 = (const float*)d_in[2];
    const float* b_ih0 = (const float*)d_in[3];
    const float* b_hh0 = (const float*)d_in[4];
    const float* w_ih1 = (const float*)d_in[5];
    const float* w_hh1 = (const float*)d_in[6];
    const float* b_ih1 = (const float*)d_in[7];
    const float* b_hh1 = (const float*)d_in[8];
    const float* fc1_w = (const float*)d_in[9];
    const float* fc1_b = (const float*)d_in[10];
    const float* fc2_w = (const float*)d_in[11];
    const float* fc2_b = (const float*)d_in[12];
    float* out = (float*)d_out;

    dim3 grid(B_), block(832);
    hipLaunchKernelGGL(lstm_fused3, grid, block, 0, stream,
                       x, w_ih0, w_hh0, b_ih0, b_hh0,
                       w_ih1, w_hh1, b_ih1, b_hh1,
                       fc1_w, fc1_b, fc2_w, fc2_b, out);
}

// Round 4
// 2204.744 us; speedup vs baseline: 1.3490x; 1.3490x over previous
//
#include <hip/hip_runtime.h>

#define B_    1024
#define T_    512
#define I_    16
#define H_    50
#define FC_   64
#define HALFW 28    // half of padded H
#define HP    56    // padded H for float4 reads

__device__ __forceinline__ float sigm(float x)   { return 1.0f / (1.0f + __expf(-x)); }
__device__ __forceinline__ float tanh_f(float x) { return 1.0f - 2.0f / (1.0f + __expf(2.0f * x)); }

// 2 batch rows per block. Lane layout (tid < 400): tid = 8*u + 2*q + s
//   u = unit (0..49), q = gate (i,f,g,o), s = dot-product half.
// All 8 lanes of a unit in one wave -> gate exchange via shuffles; c in regs.
// 92 weight floats/lane pinned in VGPRs via opaque asm (defeats remat/sink);
// waves_per_eu(2,2) gives a 256-VGPR budget so the allocator doesn't squeeze.
__global__ __launch_bounds__(448) __attribute__((amdgpu_waves_per_eu(2, 2)))
void lstm_fused4(
    const float* __restrict__ x,
    const float* __restrict__ w_ih0, const float* __restrict__ w_hh0,
    const float* __restrict__ b_ih0, const float* __restrict__ b_hh0,
    const float* __restrict__ w_ih1, const float* __restrict__ w_hh1,
    const float* __restrict__ b_ih1, const float* __restrict__ b_hh1,
    const float* __restrict__ fc1_w, const float* __restrict__ fc1_b,
    const float* __restrict__ fc2_w, const float* __restrict__ fc2_b,
    float* __restrict__ out)
{
    __shared__ float h0s[2][2][HP], h1s[2][2][HP];   // [pingpong][row][HP]
    __shared__ float xs[4][2][I_];                   // prefetch ring, distance 2

    const int tid  = threadIdx.x;
    const int row0 = blockIdx.x * 2;
    const int u    = tid >> 3;
    const int q    = (tid >> 1) & 3;
    const int s    = tid & 1;
    const bool gl  = tid < 400;
    const int uc   = (u < H_) ? u : (H_ - 1);        // clamped for lanes >= 400
    const int g    = q * H_ + uc;
    const int base = tid & ~7;

    // ---- persistent weights: 8 + 3*28 = 92 floats, loaded unconditionally ----
    float w0x[8], w0h[HALFW], w1x[HALFW], w1h[HALFW];
    #pragma unroll
    for (int i = 0; i < 8; ++i) w0x[i] = w_ih0[g * I_ + s * 8 + i];
    #pragma unroll
    for (int j = 0; j < HALFW; ++j) {
        const int jj = s * HALFW + j;
        const bool v = jj < H_;
        w0h[j] = v ? w_hh0[g * H_ + jj] : 0.f;
        w1x[j] = v ? w_ih1[g * H_ + jj] : 0.f;
        w1h[j] = v ? w_hh1[g * H_ + jj] : 0.f;
    }
    float bias0 = (s == 0) ? (b_ih0[g] + b_hh0[g]) : 0.f;
    float bias1 = (s == 0) ? (b_ih1[g] + b_hh1[g]) : 0.f;

    // ---- pin everything in VGPRs: opaque to LICM/remat ----
    #pragma unroll
    for (int i = 0; i < 8; ++i) asm volatile("" : "+v"(w0x[i]));
    #pragma unroll
    for (int j = 0; j < HALFW; ++j) {
        asm volatile("" : "+v"(w0h[j]));
        asm volatile("" : "+v"(w1x[j]));
        asm volatile("" : "+v"(w1h[j]));
    }
    asm volatile("" : "+v"(bias0));
    asm volatile("" : "+v"(bias1));

    if (tid < 2 * 2 * HP) {                          // zero h incl. padding
        ((float*)h0s)[tid] = 0.f;
        ((float*)h1s)[tid] = 0.f;
    }
    if (tid < 16) {                                  // stage x(0), x(1), both rows
        const int tt = tid >> 3, r = (tid >> 2) & 1, i4 = (tid & 3) * 4;
        *(float4*)&xs[tt][r][i4] =
            *(const float4*)(x + ((size_t)(row0 + r) * T_ + tt) * I_ + i4);
    }
    float c00 = 0.f, c01 = 0.f, c10 = 0.f, c11 = 0.f;  // c[layer][row]
    __syncthreads();

    for (int t = 0; t < T_; ++t) {
        const int p = t & 1;                         // read h*[p], write h*[1-p]

        // ---- P0: layer-0 gates + cell update (x prefetch on idle lanes) ----
        if (gl) {
            float a0 = bias0, a1 = bias0;
            const float4* xp0 = (const float4*)(xs[t & 3][0] + s * 8);
            const float4* xp1 = (const float4*)(xs[t & 3][1] + s * 8);
            float4 v00 = xp0[0], v01 = xp0[1], v10 = xp1[0], v11 = xp1[1];
            a0 += w0x[0]*v00.x + w0x[1]*v00.y + w0x[2]*v00.z + w0x[3]*v00.w
                + w0x[4]*v01.x + w0x[5]*v01.y + w0x[6]*v01.z + w0x[7]*v01.w;
            a1 += w0x[0]*v10.x + w0x[1]*v10.y + w0x[2]*v10.z + w0x[3]*v10.w
                + w0x[4]*v11.x + w0x[5]*v11.y + w0x[6]*v11.z + w0x[7]*v11.w;
            const float4* h00 = (const float4*)(h0s[p][0] + s * HALFW);
            const float4* h01 = (const float4*)(h0s[p][1] + s * HALFW);
            #pragma unroll
            for (int k = 0; k < 7; ++k) {
                float4 a = h00[k], b = h01[k];
                a0 += w0h[4*k]*a.x + w0h[4*k+1]*a.y + w0h[4*k+2]*a.z + w0h[4*k+3]*a.w;
                a1 += w0h[4*k]*b.x + w0h[4*k+1]*b.y + w0h[4*k+2]*b.z + w0h[4*k+3]*b.w;
            }
            a0 += __shfl_xor(a0, 1);
            a1 += __shfl_xor(a1, 1);
            const float act0 = (q == 2) ? tanh_f(a0) : sigm(a0);
            const float act1 = (q == 2) ? tanh_f(a1) : sigm(a1);
            const float gi0 = __shfl(act0, base),     gi1 = __shfl(act1, base);
            const float gf0 = __shfl(act0, base + 2), gf1 = __shfl(act1, base + 2);
            const float gg0 = __shfl(act0, base + 4), gg1 = __shfl(act1, base + 4);
            const float go0 = __shfl(act0, base + 6), go1 = __shfl(act1, base + 6);
            c00 = gf0 * c00 + gi0 * gg0;
            c01 = gf1 * c01 + gi1 * gg1;
            if ((tid & 7) == 0) {
                h0s[1 - p][0][u] = go0 * tanh_f(c00);
                h0s[1 - p][1][u] = go1 * tanh_f(c01);
            }
        } else if (tid >= 416 && tid < 424) {
            if (t + 2 < T_) {
                const int idx = tid - 416, r = idx >> 2, i4 = (idx & 3) * 4;
                *(float4*)&xs[(t + 2) & 3][r][i4] =
                    *(const float4*)(x + ((size_t)(row0 + r) * T_ + t + 2) * I_ + i4);
            }
        }
        __syncthreads();

        // ---- P1: layer-1 gates + cell update ----
        if (gl) {
            float a0 = bias1, a1 = bias1;
            const float4* g00 = (const float4*)(h0s[1 - p][0] + s * HALFW);
            const float4* g01 = (const float4*)(h0s[1 - p][1] + s * HALFW);
            const float4* g10 = (const float4*)(h1s[p][0]     + s * HALFW);
            const float4* g11 = (const float4*)(h1s[p][1]     + s * HALFW);
            #pragma unroll
            for (int k = 0; k < 7; ++k) {
                float4 a = g00[k], b = g01[k];
                a0 += w1x[4*k]*a.x + w1x[4*k+1]*a.y + w1x[4*k+2]*a.z + w1x[4*k+3]*a.w;
                a1 += w1x[4*k]*b.x + w1x[4*k+1]*b.y + w1x[4*k+2]*b.z + w1x[4*k+3]*b.w;
            }
            #pragma unroll
            for (int k = 0; k < 7; ++k) {
                float4 a = g10[k], b = g11[k];
                a0 += w1h[4*k]*a.x + w1h[4*k+1]*a.y + w1h[4*k+2]*a.z + w1h[4*k+3]*a.w;
                a1 += w1h[4*k]*b.x + w1h[4*k+1]*b.y + w1h[4*k+2]*b.z + w1h[4*k+3]*b.w;
            }
            a0 += __shfl_xor(a0, 1);
            a1 += __shfl_xor(a1, 1);
            const float act0 = (q == 2) ? tanh_f(a0) : sigm(a0);
            const float act1 = (q == 2) ? tanh_f(a1) : sigm(a1);
            const float gi0 = __shfl(act0, base),     gi1 = __shfl(act1, base);
            const float gf0 = __shfl(act0, base + 2), gf1 = __shfl(act1, base + 2);
            const float gg0 = __shfl(act0, base + 4), gg1 = __shfl(act1, base + 4);
            const float go0 = __shfl(act0, base + 6), go1 = __shfl(act1, base + 6);
            c10 = gf0 * c10 + gi0 * gg0;
            c11 = gf1 * c11 + gi1 * gg1;
            if ((tid & 7) == 0) {
                h1s[1 - p][0][u] = go0 * tanh_f(c10);
                h1s[1 - p][1][u] = go1 * tanh_f(c11);
            }
        }
        __syncthreads();
    }

    // ---- FC epilogue: final h1 in h1s[0][r] (T even). Row r on wave r. ----
    if (tid < 2 * FC_) {
        const int r = tid >> 6, uu = tid & 63;
        const float* hf = h1s[0][r];
        float a = fc1_b[uu];
        #pragma unroll
        for (int j = 0; j < H_; ++j) a += fc1_w[uu * H_ + j] * hf[j];
        float rsum = fmaxf(a, 0.f) * fc2_w[uu];
        #pragma unroll
        for (int off = 1; off < FC_; off <<= 1) rsum += __shfl_xor(rsum, off);
        if (uu == 0) out[row0 + r] = rsum + fc2_b[0];
    }
}

extern "C" void kernel_launch(void* const* d_in, const int* in_sizes, int n_in,
                              void* d_out, int out_size, void* d_ws, size_t ws_size,
                              hipStream_t stream) {
    const float* x     = (const float*)d_in[0];
    const float* w_ih0 = (const float*)d_in[1];
    const float* w_hh0 = (const float*)d_in[2];
    const float* b_ih0 = (const float*)d_in[3];
    const float* b_hh0 = (const float*)d_in[4];
    const float* w_ih1 = (const float*)d_in[5];
    const float* w_hh1 = (const float*)d_in[6];
    const float* b_ih1 = (const float*)d_in[7];
    const float* b_hh1 = (const float*)d_in[8];
    const float* fc1_w = (const float*)d_in[9];
    const float* fc1_b = (const float*)d_in[10];
    const float* fc2_w = (const float*)d_in[11];
    const float* fc2_b = (const float*)d_in[12];
    float* out = (float*)d_out;

    dim3 grid(B_ / 2), block(448);
    hipLaunchKernelGGL(lstm_fused4, grid, block, 0, stream,
                       x, w_ih0, w_hh0, b_ih0, b_hh0,
                       w_ih1, w_hh1, b_ih1, b_hh1,
                       fc1_w, fc1_b, fc2_w, fc2_b, out);
}